// Round 1
// baseline (708.075 us; speedup 1.0000x reference)
//
#include <hip/hip_runtime.h>

#define BATCH_N 100000
#define ROW 592
// largest padded tile: block 1 -> 64 rows * (192+1) floats
#define LDS_FLOATS (64 * 193)

// out[z, w, i] = pw * sum_u W[u, w] * x[z, u, i]   per irrep block
// lane <-> z (64 rows per wave), wave <-> w-chunk (MUL/4 outputs per wave)
// W reads are wave-uniform -> s_load + v_fmac with SGPR operand.
template<int MUL, int DIM, int DOFF, int WOFF>
__device__ __forceinline__ void block_lin(const float* __restrict__ x,
                                          const float* __restrict__ w,
                                          float* __restrict__ out,
                                          float* __restrict__ lds,
                                          int z0, int lane, int wbase,
                                          int tid, bool valid, float pw)
{
    constexpr int S = MUL * DIM;      // slice width in floats
    constexpr int P = S + 1;          // odd LDS row stride -> conflict-free lane reads

    __syncthreads();                  // previous phase's compute done before overwrite

    // ---- stage 64 x S slice into LDS (coalesced global dwords, conflict-free ds_write)
    for (int idx = tid; idx < 64 * S; idx += 256) {
        int z = idx / S;              // compile-time magic-mul
        int c = idx - z * S;
        float v = 0.f;
        if (z0 + z < BATCH_N)
            v = x[(size_t)(z0 + z) * ROW + DOFF + c];
        lds[z * P + c] = v;
    }
    __syncthreads();

    // ---- compute: this wave covers w in [wbase, wbase + MUL/4)
    constexpr int WCH = MUL / 4;
    float acc[WCH * DIM];
    #pragma unroll
    for (int k = 0; k < WCH * DIM; ++k) acc[k] = 0.f;

    const float* xr = lds + lane * P;         // this lane's row
    const float* wp = w + WOFF + wbase;       // wave-uniform base

    #pragma unroll 4
    for (int u = 0; u < MUL; ++u) {
        float xv[DIM];
        #pragma unroll
        for (int i = 0; i < DIM; ++i) xv[i] = xr[u * DIM + i];
        #pragma unroll
        for (int wi = 0; wi < WCH; ++wi) {
            float wv = wp[u * MUL + wi];      // uniform -> s_load
            #pragma unroll
            for (int i = 0; i < DIM; ++i)
                acc[wi * DIM + i] = fmaf(wv, xv[i], acc[wi * DIM + i]);
        }
    }

    // ---- store: per-lane contiguous WCH*DIM floats (all multiples of 4 dwords, 16B aligned)
    if (valid) {
        float* orow = out + (size_t)(z0 + lane) * ROW + DOFF + wbase * DIM;
        #pragma unroll
        for (int k = 0; k < WCH * DIM; k += 4) {
            float4 v;
            v.x = pw * acc[k + 0];
            v.y = pw * acc[k + 1];
            v.z = pw * acc[k + 2];
            v.w = pw * acc[k + 3];
            *reinterpret_cast<float4*>(orow + k) = v;
        }
    }
}

__global__ __launch_bounds__(256, 3)
void irrep_linear_kernel(const float* __restrict__ x,
                         const float* __restrict__ w,
                         float* __restrict__ out)
{
    __shared__ float lds[LDS_FLOATS];
    const int tid  = threadIdx.x;
    const int lane = tid & 63;
    const int wave = tid >> 6;
    const int z0   = blockIdx.x * 64;
    const bool valid = (z0 + lane) < BATCH_N;

    // MULS = {128,64,32,16}, DIMS = {1,3,5,7}
    // x/out col offsets: 0,128,320,480 ; W offsets: 0,16384,20480,21504
    block_lin<128, 1,   0,     0>(x, w, out, lds, z0, lane,
        __builtin_amdgcn_readfirstlane(wave * 32), tid, valid, 0.0883883476483184406f); // 128^-0.5
    block_lin< 64, 3, 128, 16384>(x, w, out, lds, z0, lane,
        __builtin_amdgcn_readfirstlane(wave * 16), tid, valid, 0.125f);                 // 64^-0.5
    block_lin< 32, 5, 320, 20480>(x, w, out, lds, z0, lane,
        __builtin_amdgcn_readfirstlane(wave *  8), tid, valid, 0.176776695296636881f);  // 32^-0.5
    block_lin< 16, 7, 480, 21504>(x, w, out, lds, z0, lane,
        __builtin_amdgcn_readfirstlane(wave *  4), tid, valid, 0.25f);                  // 16^-0.5
}

extern "C" void kernel_launch(void* const* d_in, const int* in_sizes, int n_in,
                              void* d_out, int out_size, void* d_ws, size_t ws_size,
                              hipStream_t stream)
{
    (void)in_sizes; (void)n_in; (void)out_size; (void)d_ws; (void)ws_size;
    const float* x = (const float*)d_in[0];
    const float* w = (const float*)d_in[1];
    float* out    = (float*)d_out;

    const int nwg = (BATCH_N + 63) / 64;   // 1563 workgroups, 64 rows each
    irrep_linear_kernel<<<nwg, 256, 0, stream>>>(x, w, out);
}

// Round 4
// 493.483 us; speedup vs baseline: 1.4349x; 1.4349x over previous
//
#include <hip/hip_runtime.h>

#define BATCH_N 100000
#define ROW 592
#define ZTILES 1563                      // ceil(100000/64)
// largest tile: block 1 -> 64 rows * (192+1) floats = 49408 B; round up
#define LDS_FLOATS (64 * 193)

// One WG = one irrep block x one 64-row z-tile. Single stage->barrier->compute.
// lane <-> z row, wave <-> w-chunk (MUL/4 cols); W reads wave-uniform -> s_load.
template<int MUL, int DIM, int DOFF, int WOFF>
__device__ __forceinline__ void do_block(const float* __restrict__ x,
                                         const float* __restrict__ w,
                                         float* __restrict__ out,
                                         float* __restrict__ lds,
                                         int zb, float pw)
{
    constexpr int S   = MUL * DIM;       // slice width (floats): 128,192,160,112
    constexpr int P   = S + 1;           // odd LDS stride -> conflict-free lane reads
    constexpr int S4  = S / 4;           // float4 per row
    constexpr int NV4 = S4 * 64 / 256;   // float4 loads per thread: 8,12,10,7

    const int tid  = threadIdx.x;
    const int lane = tid & 63;
    const int wave = tid >> 6;
    const int z0   = zb * 64;

    // ---- stage: all global loads first (one vmcnt batch), then LDS writes
    float4 tmp[NV4];
    #pragma unroll
    for (int k = 0; k < NV4; ++k) {
        const int idx = tid + k * 256;        // over 64 * S4
        const int z   = idx / S4;
        const int c4  = idx - z * S4;
        if (z0 + z < BATCH_N)
            tmp[k] = *reinterpret_cast<const float4*>(
                x + (size_t)(z0 + z) * ROW + DOFF + c4 * 4);
        else
            tmp[k] = make_float4(0.f, 0.f, 0.f, 0.f);
    }
    #pragma unroll
    for (int k = 0; k < NV4; ++k) {
        const int idx = tid + k * 256;
        const int z   = idx / S4;
        const int c4  = idx - z * S4;
        float* p = lds + z * P + c4 * 4;
        p[0] = tmp[k].x; p[1] = tmp[k].y; p[2] = tmp[k].z; p[3] = tmp[k].w;
    }
    __syncthreads();

    // ---- compute: this wave covers w in [wbase, wbase + MUL/4)
    constexpr int WCH = MUL / 4;
    const int wbase = __builtin_amdgcn_readfirstlane(wave * WCH);

    float acc[WCH * DIM];
    #pragma unroll
    for (int k = 0; k < WCH * DIM; ++k) acc[k] = 0.f;

    const float* xr = lds + lane * P;          // this lane's row
    const float* wp = w + WOFF + wbase;        // wave-uniform base

    #pragma unroll 4
    for (int u = 0; u < MUL; ++u) {
        float xv[DIM];
        #pragma unroll
        for (int i = 0; i < DIM; ++i) xv[i] = xr[u * DIM + i];
        #pragma unroll
        for (int wi = 0; wi < WCH; ++wi) {
            const float wv = wp[u * MUL + wi]; // uniform -> scalar load
            #pragma unroll
            for (int i = 0; i < DIM; ++i)
                acc[wi * DIM + i] = fmaf(wv, xv[i], acc[wi * DIM + i]);
        }
    }

    // ---- store: per-lane contiguous WCH*DIM floats (divisible by 4, 16B aligned)
    if (z0 + lane < BATCH_N) {
        float* orow = out + (size_t)(z0 + lane) * ROW + DOFF + wbase * DIM;
        #pragma unroll
        for (int k = 0; k < WCH * DIM; k += 4) {
            float4 v;
            v.x = pw * acc[k + 0];
            v.y = pw * acc[k + 1];
            v.z = pw * acc[k + 2];
            v.w = pw * acc[k + 3];
            *reinterpret_cast<float4*>(orow + k) = v;
        }
    }
}

__global__ __launch_bounds__(256, 3)
void irrep_linear_kernel(const float* __restrict__ x,
                         const float* __restrict__ w,
                         float* __restrict__ out)
{
    __shared__ float lds[LDS_FLOATS];
    const int bid = blockIdx.x;

    // MULS = {128,64,32,16}, DIMS = {1,3,5,7}
    // x/out col offsets: 0,128,320,480 ; W offsets: 0,16384,20480,21504
    if (bid < ZTILES) {
        do_block<128, 1,   0,     0>(x, w, out, lds, bid,            0.0883883476483184406f);
    } else if (bid < 2 * ZTILES) {
        do_block< 64, 3, 128, 16384>(x, w, out, lds, bid - ZTILES,   0.125f);
    } else if (bid < 3 * ZTILES) {
        do_block< 32, 5, 320, 20480>(x, w, out, lds, bid - 2*ZTILES, 0.176776695296636881f);
    } else {
        do_block< 16, 7, 480, 21504>(x, w, out, lds, bid - 3*ZTILES, 0.25f);
    }
}

extern "C" void kernel_launch(void* const* d_in, const int* in_sizes, int n_in,
                              void* d_out, int out_size, void* d_ws, size_t ws_size,
                              hipStream_t stream)
{
    (void)in_sizes; (void)n_in; (void)out_size; (void)d_ws; (void)ws_size;
    const float* x = (const float*)d_in[0];
    const float* w = (const float*)d_in[1];
    float* out    = (float*)d_out;

    irrep_linear_kernel<<<4 * ZTILES, 256, 0, stream>>>(x, w, out);
}